// Round 1
// baseline (885.569 us; speedup 1.0000x reference)
//
#include <hip/hip_runtime.h>
#include <stdint.h>

// SelectiveSSM (Mamba block) for MI355X / gfx950.
// Pipeline: LN -> GEMM1(bf16 MFMA) -> conv+SiLU -> x_proj -> scan(+gate) -> GEMM3(+residual)

typedef short short8 __attribute__((ext_vector_type(8)));
typedef float f32x4 __attribute__((ext_vector_type(4)));

#define DEV static __device__ __forceinline__

constexpr int BATCH = 2, SEQ = 2048, DM = 1024, DI = 2048, NST = 16;
constexpr int NTOK = BATCH * SEQ;  // 4096

DEV float bf2f(ushort h) {
    union { uint u; float f; } c; c.u = ((uint)h) << 16; return c.f;
}
DEV ushort f2bf(float x) {
    union { uint u; float f; } c; c.f = x;
    uint u = c.u;
    uint r = (u + 0x7FFFu + ((u >> 16) & 1u)) >> 16;   // RNE
    return (ushort)r;
}

// ---------------- transpose + fp32->bf16 convert: W[K][N] -> Bt[N][K] ----------------
__global__ __launch_bounds__(256) void transpose_bf16(const float* __restrict__ W,
                                                      ushort* __restrict__ Bt,
                                                      int K, int N) {
    __shared__ float tile[32][33];
    int tx = threadIdx.x;          // 0..31
    int ty = threadIdx.y;          // 0..7
    int n0 = blockIdx.x * 32;
    int k0 = blockIdx.y * 32;
#pragma unroll
    for (int i = 0; i < 32; i += 8)
        tile[ty + i][tx] = W[(size_t)(k0 + ty + i) * N + n0 + tx];
    __syncthreads();
#pragma unroll
    for (int i = 0; i < 32; i += 8)
        Bt[(size_t)(n0 + ty + i) * K + k0 + tx] = f2bf(tile[tx][ty + i]);
}

// ---------------- LayerNorm: x fp32 (4096x1024) -> xn bf16 ----------------
__global__ __launch_bounds__(256) void ln_kernel(const float* __restrict__ x,
                                                 const float* __restrict__ g,
                                                 const float* __restrict__ b,
                                                 ushort* __restrict__ xn) {
    int row = blockIdx.x;
    int tid = threadIdx.x;
    const float4 v = ((const float4*)(x + (size_t)row * DM))[tid];
    float s = v.x + v.y + v.z + v.w;
    float sq = v.x * v.x + v.y * v.y + v.z * v.z + v.w * v.w;
#pragma unroll
    for (int o = 32; o; o >>= 1) { s += __shfl_down(s, o); sq += __shfl_down(sq, o); }
    __shared__ float ls[4], lsq[4];
    __shared__ float smu, srs;
    int wid = tid >> 6;
    if ((tid & 63) == 0) { ls[wid] = s; lsq[wid] = sq; }
    __syncthreads();
    if (tid == 0) {
        float S = ls[0] + ls[1] + ls[2] + ls[3];
        float SQ = lsq[0] + lsq[1] + lsq[2] + lsq[3];
        float mu = S / DM;
        float var = SQ / DM - mu * mu;
        smu = mu; srs = rsqrtf(var + 1e-5f);
    }
    __syncthreads();
    float mu = smu, rs = srs;
    const float4 gg = ((const float4*)g)[tid];
    const float4 bb = ((const float4*)b)[tid];
    ushort4 o;
    o.x = f2bf((v.x - mu) * rs * gg.x + bb.x);
    o.y = f2bf((v.y - mu) * rs * gg.y + bb.y);
    o.z = f2bf((v.z - mu) * rs * gg.z + bb.z);
    o.w = f2bf((v.w - mu) * rs * gg.w + bb.w);
    ((ushort4*)(xn + (size_t)row * DM))[tid] = o;
}

// ---------------- bf16 MFMA GEMM: C[M][N] = A[M][K] * Bt[N][K]^T (+res) ----------------
// 128x128 tile, BK=32, 256 threads (4 waves 2x2), each wave 64x64 (4x4 frags of 16x16).
template <typename OUT_T, bool RES>
__global__ __launch_bounds__(256) void gemm_bf16(const ushort* __restrict__ A,
                                                 const ushort* __restrict__ Bt,
                                                 OUT_T* __restrict__ C,
                                                 const float* __restrict__ res,
                                                 int M, int N, int K) {
    __shared__ __align__(16) ushort Als[128][40];  // pad 40: 80B row stride, 16B-aligned
    __shared__ __align__(16) ushort Bls[128][40];
    int tid = threadIdx.x;
    int lane = tid & 63, w = tid >> 6;
    int wm = w >> 1, wn = w & 1;
    int m0 = blockIdx.y * 128, n0 = blockIdx.x * 128;
    int lr = lane & 15, kc = lane >> 4;

    f32x4 acc[4][4];
#pragma unroll
    for (int i = 0; i < 4; i++)
#pragma unroll
        for (int j = 0; j < 4; j++) acc[i][j] = (f32x4){0.f, 0.f, 0.f, 0.f};

    int r0 = tid >> 2, c0 = (tid & 3) * 8;
    const size_t arow0 = (size_t)(m0 + r0) * K;
    const size_t arow1 = (size_t)(m0 + r0 + 64) * K;
    const size_t brow0 = (size_t)(n0 + r0) * K;
    const size_t brow1 = (size_t)(n0 + r0 + 64) * K;

    for (int k0 = 0; k0 < K; k0 += 32) {
        *(uint4*)&Als[r0][c0]      = *(const uint4*)(A + arow0 + k0 + c0);
        *(uint4*)&Als[r0 + 64][c0] = *(const uint4*)(A + arow1 + k0 + c0);
        *(uint4*)&Bls[r0][c0]      = *(const uint4*)(Bt + brow0 + k0 + c0);
        *(uint4*)&Bls[r0 + 64][c0] = *(const uint4*)(Bt + brow1 + k0 + c0);
        __syncthreads();
        short8 af[4], bfr[4];
#pragma unroll
        for (int mi = 0; mi < 4; mi++) af[mi] = *(const short8*)&Als[wm * 64 + mi * 16 + lr][kc * 8];
#pragma unroll
        for (int ni = 0; ni < 4; ni++) bfr[ni] = *(const short8*)&Bls[wn * 64 + ni * 16 + lr][kc * 8];
#pragma unroll
        for (int mi = 0; mi < 4; mi++)
#pragma unroll
            for (int ni = 0; ni < 4; ni++)
                acc[mi][ni] = __builtin_amdgcn_mfma_f32_16x16x32_bf16(af[mi], bfr[ni], acc[mi][ni], 0, 0, 0);
        __syncthreads();
    }

#pragma unroll
    for (int mi = 0; mi < 4; mi++) {
        int r = m0 + wm * 64 + mi * 16 + (lane >> 4) * 4;
#pragma unroll
        for (int ni = 0; ni < 4; ni++) {
            int cc = n0 + wn * 64 + ni * 16 + lr;
#pragma unroll
            for (int j = 0; j < 4; j++) {
                float v = acc[mi][ni][j];
                size_t off = (size_t)(r + j) * N + cc;
                if (RES) v += res[off];
                if constexpr (sizeof(OUT_T) == 2) C[off] = f2bf(v);
                else C[off] = v;
            }
        }
    }
}

// ---------------- depthwise causal conv (width 4) + SiLU ----------------
// xz bf16 (4096 x 4096), x_b = xz[:, :2048]; u fp32 (4096 x 2048)
__global__ __launch_bounds__(256) void conv_silu(const ushort* __restrict__ xz,
                                                 const float* __restrict__ cw,
                                                 const float* __restrict__ cb,
                                                 float* __restrict__ u) {
    int idx = blockIdx.x * 256 + threadIdx.x;   // 8.4M
    int d = idx & (DI - 1);
    int row = idx >> 11;
    int t = row & (SEQ - 1);
    int b = row >> 11;
    float4 w4 = *(const float4*)(cw + (size_t)d * 4);
    float acc = cb[d];
    const float wk[4] = {w4.x, w4.y, w4.z, w4.w};
#pragma unroll
    for (int k = 0; k < 4; k++) {
        int tt = t - 3 + k;
        if (tt >= 0)
            acc += bf2f(xz[(size_t)(b * SEQ + tt) * (2 * DI) + d]) * wk[k];
    }
    u[idx] = acc / (1.f + __expf(-acc));   // SiLU
}

// ---------------- x_proj: params[33] = u_row(2048) @ W(2048x33); split B/C/pdt ----------------
__global__ __launch_bounds__(64) void xproj(const float* __restrict__ u,
                                            const float* __restrict__ W,
                                            float* __restrict__ Bc,
                                            float* __restrict__ Cc,
                                            float* __restrict__ pdt) {
    int row = blockIdx.x;
    int j = threadIdx.x;
    int jj = j < 33 ? j : 32;
    const float* ur = u + (size_t)row * DI;
    float acc = 0.f;
#pragma unroll 8
    for (int k = 0; k < DI; k++) acc = fmaf(ur[k], W[(size_t)k * 33 + jj], acc);
    if (j < 16) Bc[(size_t)row * 16 + j] = acc;
    else if (j < 32) Cc[(size_t)row * 16 + (j - 16)] = acc;
    else if (j == 32) pdt[row] = acc;
}

// ---------------- selective scan + gate ----------------
// 4 states/thread, 4 threads per channel (g = lane&3), 16 channels per 64-thread block.
struct Pref { float pd, uu; float4 Bv, Cv; ushort zb; };

DEV Pref scan_load(const float* __restrict__ u, const float* __restrict__ Bc,
                   const float* __restrict__ Cc, const float* __restrict__ pdt,
                   const ushort* __restrict__ xz, int b, int t, int d, int g) {
    Pref p;
    int row = b * SEQ + t;
    p.pd = pdt[row];
    p.uu = u[(size_t)row * DI + d];
    p.Bv = *(const float4*)(Bc + (size_t)row * 16 + g * 4);
    p.Cv = *(const float4*)(Cc + (size_t)row * 16 + g * 4);
    p.zb = xz[(size_t)row * (2 * DI) + DI + d];
    return p;
}

DEV void scan_step(const Pref& P, float dtw, float dtb,
                   float a0, float a1, float a2, float a3,
                   float& h0, float& h1, float& h2, float& h3,
                   ushort* __restrict__ yg, size_t orow, int d, int g) {
    float arg = fmaf(P.pd, dtw, dtb);
    float dt = (arg > 15.f) ? arg : __logf(1.f + __expf(arg));  // softplus
    float du = dt * P.uu;
    float p0 = __expf(dt * a0), p1 = __expf(dt * a1), p2 = __expf(dt * a2), p3 = __expf(dt * a3);
    h0 = fmaf(h0, p0, du * P.Bv.x);
    h1 = fmaf(h1, p1, du * P.Bv.y);
    h2 = fmaf(h2, p2, du * P.Bv.z);
    h3 = fmaf(h3, p3, du * P.Bv.w);
    float y = h0 * P.Cv.x + h1 * P.Cv.y + h2 * P.Cv.z + h3 * P.Cv.w;
    y += __shfl_xor(y, 1);
    y += __shfl_xor(y, 2);
    if (g == 0) {
        float z = bf2f(P.zb);
        float sz = z / (1.f + __expf(-z));
        yg[orow + d] = f2bf(y * sz);
    }
}

__global__ __launch_bounds__(64) void scan_kernel(const float* __restrict__ u,
                                                  const float* __restrict__ Bc,
                                                  const float* __restrict__ Cc,
                                                  const float* __restrict__ pdt,
                                                  const float* __restrict__ A_log,
                                                  const float* __restrict__ dt_w,
                                                  const float* __restrict__ dt_b,
                                                  const ushort* __restrict__ xz,
                                                  ushort* __restrict__ yg) {
    int lane = threadIdx.x;
    int blk = blockIdx.x;     // 256 = 2 batches * 128 channel-groups
    int b = blk >> 7, dg = blk & 127;
    int g = lane & 3, dl = lane >> 2;
    int d = dg * 16 + dl;
    float dtw = dt_w[d], dtb = dt_b[d];
    const float* alp = A_log + (size_t)d * NST + g * 4;
    float a0 = -expf(alp[0]), a1 = -expf(alp[1]), a2 = -expf(alp[2]), a3 = -expf(alp[3]);
    float h0 = 0.f, h1 = 0.f, h2 = 0.f, h3 = 0.f;

    Pref P0 = scan_load(u, Bc, Cc, pdt, xz, b, 0, d, g);
    Pref P1 = scan_load(u, Bc, Cc, pdt, xz, b, 1, d, g);
    for (int t = 0; t < SEQ; t += 2) {
        Pref N0 = scan_load(u, Bc, Cc, pdt, xz, b, min(t + 2, SEQ - 1), d, g);
        scan_step(P0, dtw, dtb, a0, a1, a2, a3, h0, h1, h2, h3,
                  yg, (size_t)(b * SEQ + t) * DI, d, g);
        Pref N1 = scan_load(u, Bc, Cc, pdt, xz, b, min(t + 3, SEQ - 1), d, g);
        scan_step(P1, dtw, dtb, a0, a1, a2, a3, h0, h1, h2, h3,
                  yg, (size_t)(b * SEQ + t + 1) * DI, d, g);
        P0 = N0; P1 = N1;
    }
}

// ---------------- launch ----------------
extern "C" void kernel_launch(void* const* d_in, const int* in_sizes, int n_in,
                              void* d_out, int out_size, void* d_ws, size_t ws_size,
                              hipStream_t stream) {
    const float* x    = (const float*)d_in[0];
    const float* ipw  = (const float*)d_in[1];
    const float* cw   = (const float*)d_in[2];
    const float* cb   = (const float*)d_in[3];
    const float* xpw  = (const float*)d_in[4];
    const float* alog = (const float*)d_in[5];
    const float* dtw  = (const float*)d_in[6];
    const float* dtb  = (const float*)d_in[7];
    const float* opw  = (const float*)d_in[8];
    const float* lng  = (const float*)d_in[9];
    const float* lnb  = (const float*)d_in[10];
    float* out = (float*)d_out;

    // workspace carve (~105 MB)
    char* ws = (char*)d_ws;
    size_t off = 0;
    auto carve = [&](size_t bytes) -> void* {
        void* p = ws + off;
        off = (off + bytes + 255) & ~(size_t)255;
        return p;
    };
    ushort* Bt1 = (ushort*)carve((size_t)4096 * 1024 * 2);  // in_proj^T bf16 (N=4096,K=1024)
    ushort* Bt2 = (ushort*)carve((size_t)1024 * 2048 * 2);  // out_proj^T bf16 (N=1024,K=2048)
    ushort* xn  = (ushort*)carve((size_t)NTOK * DM * 2);    // LN output bf16
    ushort* xz  = (ushort*)carve((size_t)NTOK * 2 * DI * 2);// GEMM1 out bf16 [x_b | z]
    float*  u   = (float*) carve((size_t)NTOK * DI * 4);    // conv+silu out fp32
    float*  Bc  = (float*) carve((size_t)NTOK * NST * 4);
    float*  Cc  = (float*) carve((size_t)NTOK * NST * 4);
    float*  pdt = (float*) carve((size_t)NTOK * 4);
    ushort* yg  = (ushort*)carve((size_t)NTOK * DI * 2);    // gated scan output bf16

    transpose_bf16<<<dim3(4096 / 32, 1024 / 32), dim3(32, 8), 0, stream>>>(ipw, Bt1, 1024, 4096);
    transpose_bf16<<<dim3(1024 / 32, 2048 / 32), dim3(32, 8), 0, stream>>>(opw, Bt2, 2048, 1024);
    ln_kernel<<<NTOK, 256, 0, stream>>>(x, lng, lnb, xn);
    gemm_bf16<ushort, false><<<dim3(4096 / 128, NTOK / 128), 256, 0, stream>>>(
        xn, Bt1, xz, nullptr, NTOK, 4096, 1024);
    conv_silu<<<(NTOK * DI) / 256, 256, 0, stream>>>(xz, cw, cb, u);
    xproj<<<NTOK, 64, 0, stream>>>(u, xpw, Bc, Cc, pdt);
    scan_kernel<<<256, 64, 0, stream>>>(u, Bc, Cc, pdt, alog, dtw, dtb, xz, yg);
    gemm_bf16<float, true><<<dim3(1024 / 128, NTOK / 128), 256, 0, stream>>>(
        yg, Bt2, out, x, NTOK, 1024, 2048);
}

// Round 2
// 281.856 us; speedup vs baseline: 3.1419x; 3.1419x over previous
//
#include <hip/hip_runtime.h>
#include <stdint.h>

// SelectiveSSM (Mamba block) for MI355X / gfx950.
// Pipeline: LN -> GEMM1(bf16 MFMA) -> conv+SiLU -> x_proj -> chunked scan(+gate) -> GEMM3(+residual)

typedef short short8 __attribute__((ext_vector_type(8)));
typedef float f32x4 __attribute__((ext_vector_type(4)));

#define DEV static __device__ __forceinline__

constexpr int BATCH = 2, SEQ = 2048, DM = 1024, DI = 2048, NST = 16;
constexpr int NTOK = BATCH * SEQ;  // 4096

DEV float bf2f(ushort h) {
    union { uint u; float f; } c; c.u = ((uint)h) << 16; return c.f;
}
DEV ushort f2bf(float x) {
    union { uint u; float f; } c; c.f = x;
    uint u = c.u;
    uint r = (u + 0x7FFFu + ((u >> 16) & 1u)) >> 16;   // RNE
    return (ushort)r;
}

// ---------------- transpose + fp32->bf16 convert: W[K][N] -> Bt[N][K] ----------------
__global__ __launch_bounds__(256) void transpose_bf16(const float* __restrict__ W,
                                                      ushort* __restrict__ Bt,
                                                      int K, int N) {
    __shared__ float tile[32][33];
    int tx = threadIdx.x;          // 0..31
    int ty = threadIdx.y;          // 0..7
    int n0 = blockIdx.x * 32;
    int k0 = blockIdx.y * 32;
#pragma unroll
    for (int i = 0; i < 32; i += 8)
        tile[ty + i][tx] = W[(size_t)(k0 + ty + i) * N + n0 + tx];
    __syncthreads();
#pragma unroll
    for (int i = 0; i < 32; i += 8)
        Bt[(size_t)(n0 + ty + i) * K + k0 + tx] = f2bf(tile[tx][ty + i]);
}

// x_proj_w [2048][33] fp32 -> Wt [33][2048] bf16
__global__ __launch_bounds__(256) void transpose_xpw(const float* __restrict__ W,
                                                     ushort* __restrict__ Wt) {
    int idx = blockIdx.x * 256 + threadIdx.x;
    if (idx >= 33 * DI) return;
    int j = idx / DI, k = idx - j * DI;
    Wt[idx] = f2bf(W[(size_t)k * 33 + j]);
}

// ---------------- LayerNorm: x fp32 (4096x1024) -> xn bf16 ----------------
__global__ __launch_bounds__(256) void ln_kernel(const float* __restrict__ x,
                                                 const float* __restrict__ g,
                                                 const float* __restrict__ b,
                                                 ushort* __restrict__ xn) {
    int row = blockIdx.x;
    int tid = threadIdx.x;
    const float4 v = ((const float4*)(x + (size_t)row * DM))[tid];
    float s = v.x + v.y + v.z + v.w;
    float sq = v.x * v.x + v.y * v.y + v.z * v.z + v.w * v.w;
#pragma unroll
    for (int o = 32; o; o >>= 1) { s += __shfl_down(s, o); sq += __shfl_down(sq, o); }
    __shared__ float ls[4], lsq[4];
    __shared__ float smu, srs;
    int wid = tid >> 6;
    if ((tid & 63) == 0) { ls[wid] = s; lsq[wid] = sq; }
    __syncthreads();
    if (tid == 0) {
        float S = ls[0] + ls[1] + ls[2] + ls[3];
        float SQ = lsq[0] + lsq[1] + lsq[2] + lsq[3];
        float mu = S / DM;
        float var = SQ / DM - mu * mu;
        smu = mu; srs = rsqrtf(var + 1e-5f);
    }
    __syncthreads();
    float mu = smu, rs = srs;
    const float4 gg = ((const float4*)g)[tid];
    const float4 bb = ((const float4*)b)[tid];
    ushort4 o;
    o.x = f2bf((v.x - mu) * rs * gg.x + bb.x);
    o.y = f2bf((v.y - mu) * rs * gg.y + bb.y);
    o.z = f2bf((v.z - mu) * rs * gg.z + bb.z);
    o.w = f2bf((v.w - mu) * rs * gg.w + bb.w);
    ((ushort4*)(xn + (size_t)row * DM))[tid] = o;
}

// ---------------- bf16 MFMA GEMM: C[M][N] = A[M][K] * Bt[N][K]^T (+res) ----------------
template <typename OUT_T, bool RES>
__global__ __launch_bounds__(256) void gemm_bf16(const ushort* __restrict__ A,
                                                 const ushort* __restrict__ Bt,
                                                 OUT_T* __restrict__ C,
                                                 const float* __restrict__ res,
                                                 int M, int N, int K) {
    __shared__ __align__(16) ushort Als[128][40];
    __shared__ __align__(16) ushort Bls[128][40];
    int tid = threadIdx.x;
    int lane = tid & 63, w = tid >> 6;
    int wm = w >> 1, wn = w & 1;
    int m0 = blockIdx.y * 128, n0 = blockIdx.x * 128;
    int lr = lane & 15, kc = lane >> 4;

    f32x4 acc[4][4];
#pragma unroll
    for (int i = 0; i < 4; i++)
#pragma unroll
        for (int j = 0; j < 4; j++) acc[i][j] = (f32x4){0.f, 0.f, 0.f, 0.f};

    int r0 = tid >> 2, c0 = (tid & 3) * 8;
    const size_t arow0 = (size_t)(m0 + r0) * K;
    const size_t arow1 = (size_t)(m0 + r0 + 64) * K;
    const size_t brow0 = (size_t)(n0 + r0) * K;
    const size_t brow1 = (size_t)(n0 + r0 + 64) * K;

    for (int k0 = 0; k0 < K; k0 += 32) {
        *(uint4*)&Als[r0][c0]      = *(const uint4*)(A + arow0 + k0 + c0);
        *(uint4*)&Als[r0 + 64][c0] = *(const uint4*)(A + arow1 + k0 + c0);
        *(uint4*)&Bls[r0][c0]      = *(const uint4*)(Bt + brow0 + k0 + c0);
        *(uint4*)&Bls[r0 + 64][c0] = *(const uint4*)(Bt + brow1 + k0 + c0);
        __syncthreads();
        short8 af[4], bfr[4];
#pragma unroll
        for (int mi = 0; mi < 4; mi++) af[mi] = *(const short8*)&Als[wm * 64 + mi * 16 + lr][kc * 8];
#pragma unroll
        for (int ni = 0; ni < 4; ni++) bfr[ni] = *(const short8*)&Bls[wn * 64 + ni * 16 + lr][kc * 8];
#pragma unroll
        for (int mi = 0; mi < 4; mi++)
#pragma unroll
            for (int ni = 0; ni < 4; ni++)
                acc[mi][ni] = __builtin_amdgcn_mfma_f32_16x16x32_bf16(af[mi], bfr[ni], acc[mi][ni], 0, 0, 0);
        __syncthreads();
    }

#pragma unroll
    for (int mi = 0; mi < 4; mi++) {
        int r = m0 + wm * 64 + mi * 16 + (lane >> 4) * 4;
#pragma unroll
        for (int ni = 0; ni < 4; ni++) {
            int cc = n0 + wn * 64 + ni * 16 + lr;
#pragma unroll
            for (int j = 0; j < 4; j++) {
                float v = acc[mi][ni][j];
                size_t off = (size_t)(r + j) * N + cc;
                if (RES) v += res[off];
                if constexpr (sizeof(OUT_T) == 2) C[off] = f2bf(v);
                else C[off] = v;
            }
        }
    }
}

// ---------------- depthwise causal conv (width 4) + SiLU ----------------
__global__ __launch_bounds__(256) void conv_silu(const ushort* __restrict__ xz,
                                                 const float* __restrict__ cw,
                                                 const float* __restrict__ cb,
                                                 float* __restrict__ u) {
    int idx = blockIdx.x * 256 + threadIdx.x;   // 8.4M
    int d = idx & (DI - 1);
    int row = idx >> 11;
    int t = row & (SEQ - 1);
    int b = row >> 11;
    float4 w4 = *(const float4*)(cw + (size_t)d * 4);
    float acc = cb[d];
    const float wk[4] = {w4.x, w4.y, w4.z, w4.w};
#pragma unroll
    for (int k = 0; k < 4; k++) {
        int tt = t - 3 + k;
        if (tt >= 0)
            acc += bf2f(xz[(size_t)(b * SEQ + tt) * (2 * DI) + d]) * wk[k];
    }
    u[idx] = acc / (1.f + __expf(-acc));   // SiLU
}

// ---------------- x_proj: one wave per token; Wt bf16 [33][2048] ----------------
__global__ __launch_bounds__(256) void xproj2(const float* __restrict__ u,
                                              const ushort* __restrict__ Wt,
                                              float* __restrict__ Bc,
                                              float* __restrict__ Cc,
                                              float* __restrict__ pdt) {
    int lane = threadIdx.x & 63;
    int w = threadIdx.x >> 6;
    int row = blockIdx.x * 4 + w;
    const float* ur = u + (size_t)row * DI;
    float ureg[32];
#pragma unroll
    for (int i = 0; i < 32; i++) ureg[i] = ur[i * 64 + lane];
    for (int j = 0; j < 33; j++) {
        const ushort* wr = Wt + (size_t)j * DI;
        float acc = 0.f;
#pragma unroll
        for (int i = 0; i < 32; i++) acc = fmaf(ureg[i], bf2f(wr[i * 64 + lane]), acc);
#pragma unroll
        for (int o = 32; o; o >>= 1) acc += __shfl_xor(acc, o);
        if (lane == 0) {
            if (j < 16) Bc[(size_t)row * 16 + j] = acc;
            else if (j < 32) Cc[(size_t)row * 16 + (j - 16)] = acc;
            else pdt[row] = acc;
        }
    }
}

// ---------------- chunked selective scan + gate ----------------
// Block: 512 threads = DPB(8) channels x NC(64) chunks of CL(32) steps.
// Phase A: per-chunk local scan from h=0 -> (h_end[16], sum_dt) in LDS.
// Stitch:  serial combine over chunks per (channel,state): h_start for each chunk.
// Phase B: re-scan chunk from h_start, compute y, gate with SiLU(z), write bf16.
constexpr int S_NC = 64, S_CL = 32, S_DPB = 8;

__global__ __launch_bounds__(512) void scan_chunked(const float* __restrict__ u,
                                                    const float* __restrict__ Bc,
                                                    const float* __restrict__ Cc,
                                                    const float* __restrict__ pdt,
                                                    const float* __restrict__ A_log,
                                                    const float* __restrict__ dt_w,
                                                    const float* __restrict__ dt_b,
                                                    const ushort* __restrict__ xz,
                                                    ushort* __restrict__ yg) {
    __shared__ float hend[S_NC][S_DPB][16];   // 32 KB
    __shared__ float sdt[S_NC][S_DPB];        // 2 KB
    int tid = threadIdx.x;
    int dl = tid & (S_DPB - 1);
    int c = tid >> 3;                          // 0..63
    int blk = blockIdx.x;                      // 512 = 2 * 256
    int b = blk >> 8, dg = blk & 255;
    int d = dg * S_DPB + dl;
    float dtw = dt_w[d], dtbv = dt_b[d];
    float a[16];
#pragma unroll
    for (int s = 0; s < 16; s++) a[s] = -__expf(A_log[(size_t)d * 16 + s]);

    int row0 = b * SEQ + c * S_CL;
    float h[16];
#pragma unroll
    for (int s = 0; s < 16; s++) h[s] = 0.f;
    float sumdt = 0.f;

    // Phase A: local scan (no y needed)
    for (int t = 0; t < S_CL; t++) {
        int row = row0 + t;
        float pd = pdt[row];
        float uu = u[(size_t)row * DI + d];
        float arg = fmaf(pd, dtw, dtbv);
        float dt = (arg > 15.f) ? arg : __logf(1.f + __expf(arg));
        sumdt += dt;
        float du = dt * uu;
        const f32x4* Bp = (const f32x4*)(Bc + (size_t)row * 16);
        f32x4 B0 = Bp[0], B1 = Bp[1], B2 = Bp[2], B3 = Bp[3];
#pragma unroll
        for (int r = 0; r < 4; r++) {
            h[r]      = fmaf(h[r],      __expf(dt * a[r]),      du * B0[r]);
            h[4 + r]  = fmaf(h[4 + r],  __expf(dt * a[4 + r]),  du * B1[r]);
            h[8 + r]  = fmaf(h[8 + r],  __expf(dt * a[8 + r]),  du * B2[r]);
            h[12 + r] = fmaf(h[12 + r], __expf(dt * a[12 + r]), du * B3[r]);
        }
    }
#pragma unroll
    for (int s = 0; s < 16; s++) hend[c][dl][s] = h[s];
    sdt[c][dl] = sumdt;
    __syncthreads();

    // Stitch: 128 threads, one per (channel, state), serial over chunks
    if (tid < S_DPB * 16) {
        int dl2 = tid >> 4, s = tid & 15;
        float a2 = -__expf(A_log[(size_t)(dg * S_DPB + dl2) * 16 + s]);
        float carry = 0.f;
        for (int cc = 0; cc < S_NC; cc++) {
            float prev = carry;
            carry = fmaf(carry, __expf(a2 * sdt[cc][dl2]), hend[cc][dl2][s]);
            hend[cc][dl2][s] = prev;   // h_start for chunk cc
        }
    }
    __syncthreads();

    // Phase B: re-scan with correct h_start, emit gated y
#pragma unroll
    for (int s = 0; s < 16; s++) h[s] = hend[c][dl][s];
    for (int t = 0; t < S_CL; t++) {
        int row = row0 + t;
        float pd = pdt[row];
        float uu = u[(size_t)row * DI + d];
        float arg = fmaf(pd, dtw, dtbv);
        float dt = (arg > 15.f) ? arg : __logf(1.f + __expf(arg));
        float du = dt * uu;
        const f32x4* Bp = (const f32x4*)(Bc + (size_t)row * 16);
        const f32x4* Cp = (const f32x4*)(Cc + (size_t)row * 16);
        f32x4 B0 = Bp[0], B1 = Bp[1], B2 = Bp[2], B3 = Bp[3];
        f32x4 C0 = Cp[0], C1 = Cp[1], C2 = Cp[2], C3 = Cp[3];
        float y = 0.f;
#pragma unroll
        for (int r = 0; r < 4; r++) {
            h[r]      = fmaf(h[r],      __expf(dt * a[r]),      du * B0[r]);
            h[4 + r]  = fmaf(h[4 + r],  __expf(dt * a[4 + r]),  du * B1[r]);
            h[8 + r]  = fmaf(h[8 + r],  __expf(dt * a[8 + r]),  du * B2[r]);
            h[12 + r] = fmaf(h[12 + r], __expf(dt * a[12 + r]), du * B3[r]);
            y += h[r] * C0[r] + h[4 + r] * C1[r] + h[8 + r] * C2[r] + h[12 + r] * C3[r];
        }
        float z = bf2f(xz[(size_t)row * (2 * DI) + DI + d]);
        float sz = z / (1.f + __expf(-z));
        yg[(size_t)row * DI + d] = f2bf(y * sz);
    }
}

// ---------------- launch ----------------
extern "C" void kernel_launch(void* const* d_in, const int* in_sizes, int n_in,
                              void* d_out, int out_size, void* d_ws, size_t ws_size,
                              hipStream_t stream) {
    const float* x    = (const float*)d_in[0];
    const float* ipw  = (const float*)d_in[1];
    const float* cw   = (const float*)d_in[2];
    const float* cb   = (const float*)d_in[3];
    const float* xpw  = (const float*)d_in[4];
    const float* alog = (const float*)d_in[5];
    const float* dtw  = (const float*)d_in[6];
    const float* dtb  = (const float*)d_in[7];
    const float* opw  = (const float*)d_in[8];
    const float* lng  = (const float*)d_in[9];
    const float* lnb  = (const float*)d_in[10];
    float* out = (float*)d_out;

    char* ws = (char*)d_ws;
    size_t off = 0;
    auto carve = [&](size_t bytes) -> void* {
        void* p = ws + off;
        off = (off + bytes + 255) & ~(size_t)255;
        return p;
    };
    ushort* Bt1 = (ushort*)carve((size_t)4096 * 1024 * 2);  // in_proj^T bf16
    ushort* Bt2 = (ushort*)carve((size_t)1024 * 2048 * 2);  // out_proj^T bf16
    ushort* Wtx = (ushort*)carve((size_t)33 * DI * 2);      // x_proj^T bf16
    ushort* xn  = (ushort*)carve((size_t)NTOK * DM * 2);
    ushort* xz  = (ushort*)carve((size_t)NTOK * 2 * DI * 2);
    float*  u   = (float*) carve((size_t)NTOK * DI * 4);
    float*  Bc  = (float*) carve((size_t)NTOK * NST * 4);
    float*  Cc  = (float*) carve((size_t)NTOK * NST * 4);
    float*  pdt = (float*) carve((size_t)NTOK * 4);
    ushort* yg  = (ushort*)carve((size_t)NTOK * DI * 2);

    transpose_bf16<<<dim3(4096 / 32, 1024 / 32), dim3(32, 8), 0, stream>>>(ipw, Bt1, 1024, 4096);
    transpose_bf16<<<dim3(1024 / 32, 2048 / 32), dim3(32, 8), 0, stream>>>(opw, Bt2, 2048, 1024);
    transpose_xpw<<<(33 * DI + 255) / 256, 256, 0, stream>>>(xpw, Wtx);
    ln_kernel<<<NTOK, 256, 0, stream>>>(x, lng, lnb, xn);
    gemm_bf16<ushort, false><<<dim3(4096 / 128, NTOK / 128), 256, 0, stream>>>(
        xn, Bt1, xz, nullptr, NTOK, 4096, 1024);
    conv_silu<<<(NTOK * DI) / 256, 256, 0, stream>>>(xz, cw, cb, u);
    xproj2<<<NTOK / 4, 256, 0, stream>>>(u, Wtx, Bc, Cc, pdt);
    scan_chunked<<<512, 512, 0, stream>>>(u, Bc, Cc, pdt, alog, dtw, dtb, xz, yg);
    gemm_bf16<float, true><<<dim3(1024 / 128, NTOK / 128), 256, 0, stream>>>(
        yg, Bt2, out, x, NTOK, 1024, 2048);
}